// Round 13
// baseline (314.880 us; speedup 1.0000x reference)
//
#include <hip/hip_runtime.h>
#include <math.h>

#define NB  1024
#define NN  256
#define NF  4
#define NK  3
#define BIG 32
#define HID 2
#define BN_EPS 1e-5f
#define FLT_BIG 3.402823466e38f

typedef float f32x16 __attribute__((ext_vector_type(16)));
typedef float f32x4v __attribute__((ext_vector_type(4)));

static __device__ __forceinline__ f32x16 splat16(float s) {
    f32x16 v;
#pragma unroll
    for (int k = 0; k < 16; ++k) v[k] = s;
    return v;
}
static __device__ __forceinline__ f32x16 relu16(f32x16 v) {
    return __builtin_elementwise_max(v, splat16(0.0f));
}
static __device__ __forceinline__ f32x16 ldw16(const float* __restrict__ p) {
    return *(const f32x16*)p;   // uniform addr -> s_load_dwordx16
}
static __device__ __forceinline__ f32x4v ldw4(const float* __restrict__ p) {
    return *(const f32x4v*)p;
}
static __device__ __forceinline__ f32x4v splat4(float s) {
    f32x4v v; v[0] = s; v[1] = s; v[2] = s; v[3] = s; return v;
}

#define ROW1(s, base, Aa, Ab) { \
    f32x16 w0_ = ldw16(base); f32x16 w1_ = ldw16((base) + 16); \
    f32x16 sv_ = splat16(s); Aa += sv_ * w0_; Ab += sv_ * w1_; }

#define L2S(wbase, bbase, COFF, INa, INb, Q) \
    f32x16 Q = ldw16((bbase) + (COFF)); \
    _Pragma("unroll") \
    for (int i_ = 0; i_ < 16; i_++) { \
        f32x16 w_ = ldw16((wbase) + i_ * BIG + (COFF)); \
        Q += splat16(INa[i_]) * w_; } \
    _Pragma("unroll") \
    for (int i_ = 0; i_ < 16; i_++) { \
        f32x16 w_ = ldw16((wbase) + (16 + i_) * BIG + (COFF)); \
        Q += splat16(INb[i_]) * w_; } \
    Q = relu16(Q);

#define L3ES(COFF, Q) { \
    f32x16 wA_ = ldw16(ew3 + (COFF) * 2); \
    f32x16 wB_ = ldw16(ew3 + (COFF) * 2 + 16); \
    _Pragma("unroll") \
    for (int i_ = 0; i_ < 8; i_++) { \
        o0e2 += Q[i_] * wA_[2 * i_]; o1e2 += Q[i_] * wA_[2 * i_ + 1]; } \
    _Pragma("unroll") \
    for (int i_ = 0; i_ < 8; i_++) { \
        o0e2 += Q[8 + i_] * wB_[2 * i_]; o1e2 += Q[8 + i_] * wB_[2 * i_ + 1]; } }

#define L3DS(COFF, Q) { \
    _Pragma("unroll") \
    for (int i_ = 0; i_ < 16; i_++) { \
        f32x4v w_ = ldw4(dw3 + ((COFF) + i_) * 4); \
        ove2 += splat4(Q[i_]) * w_; } }

// top-3 streaming insert: strict <, fmed3 distances, cndmask indices.
#define KNN_UPDATE(d, m) { \
    bool c0 = (d) < d0, c1 = (d) < d1, c2 = (d) < d2; \
    i2 = c1 ? i1 : (c2 ? (m) : i2); \
    i1 = c0 ? i0 : (c1 ? (m) : i1); \
    i0 = c0 ? (m) : i0; \
    d2 = __builtin_amdgcn_fmed3f((d), d1, d2); \
    d1 = __builtin_amdgcn_fmed3f((d), d0, d1); \
    d0 = fminf((d), d0); }

// ---------------------------------------------------------------------------
__global__ void k_zero_ws(double* ws) {
    if (threadIdx.x < 8) ws[threadIdx.x] = 0.0;
}

__global__ __launch_bounds__(256) void k_bn_reduce(const float4* __restrict__ x,
                                                   double* __restrict__ ws) {
    int tid = blockIdx.x * 256 + threadIdx.x;
    double s[8] = {0, 0, 0, 0, 0, 0, 0, 0};
    for (int r = tid; r < NB * NN; r += 256 * 256) {
        float4 v = x[r];
        s[0] += v.x; s[1] += v.y; s[2] += v.z; s[3] += v.w;
        s[4] += (double)v.x * v.x; s[5] += (double)v.y * v.y;
        s[6] += (double)v.z * v.z; s[7] += (double)v.w * v.w;
    }
#pragma unroll
    for (int off = 32; off > 0; off >>= 1) {
#pragma unroll
        for (int i = 0; i < 8; i++) s[i] += __shfl_down(s[i], off);
    }
    __shared__ double red[4][8];
    int w = threadIdx.x >> 6, lane = threadIdx.x & 63;
    if (lane == 0) {
#pragma unroll
        for (int i = 0; i < 8; i++) red[w][i] = s[i];
    }
    __syncthreads();
    if (threadIdx.x == 0) {
#pragma unroll
        for (int i = 0; i < 8; i++) {
            double t = red[0][i] + red[1][i] + red[2][i] + red[3][i];
            atomicAdd(&ws[i], t);
        }
    }
}

// ---------------------------------------------------------------------------
// Phase 1: BN-normalize + encoder kNN. One block per graph. Writes h4 to
// tmp (= d_out) and packed top-3 indices (u32: i0 | i1<<8 | i2<<16) to idx.
// Low-VGPR kernel -> 8 waves/SIMD.
// ---------------------------------------------------------------------------
__global__ __launch_bounds__(256) void k_knn_enc(
    const float*  __restrict__ x,
    const float*  __restrict__ gmm, const float* __restrict__ bta,
    const double* __restrict__ bnstat,
    float4*       __restrict__ tmp,
    unsigned int* __restrict__ idx)
{
    __shared__ float4 s_h4[NN];
    __shared__ float  s_sq[NN];

    const int n = threadIdx.x;
    const int b = blockIdx.x;

    const double cnt = (double)(NB * NN);
    float mu[NF], rstd[NF];
#pragma unroll
    for (int f = 0; f < NF; f++) {
        double m   = bnstat[f] / cnt;
        double var = bnstat[4 + f] / cnt - m * m;
        mu[f]   = (float)m;
        rstd[f] = 1.0f / sqrtf((float)var + BN_EPS);
    }

    float4 xv = ((const float4*)x)[b * NN + n];
    float h0 = (xv.x - mu[0]) * rstd[0] * gmm[0] + bta[0];
    float h1 = (xv.y - mu[1]) * rstd[1] * gmm[1] + bta[1];
    float h2 = (xv.z - mu[2]) * rstd[2] * gmm[2] + bta[2];
    float h3 = (xv.w - mu[3]) * rstd[3] * gmm[3] + bta[3];
    float4 h4 = make_float4(h0, h1, h2, h3);
    s_h4[n] = h4;
    float sq = h0 * h0 + h1 * h1 + h2 * h2 + h3 * h3;
    s_sq[n] = sq;
    tmp[b * NN + n] = h4;
    __syncthreads();

    float d0 = FLT_BIG, d1 = FLT_BIG, d2 = FLT_BIG;
    int   i0 = 0, i1 = 0, i2 = 0;
    for (int m = 0; m < NN; ++m) {
        float4 a = s_h4[m];
        float dot = h0 * a.x + h1 * a.y + h2 * a.z + h3 * a.w;
        float dd = (sq + s_sq[m]) - 2.0f * dot;
        KNN_UPDATE(dd, m);
    }
    idx[b * NN + n] = (unsigned)i0 | ((unsigned)i1 << 8) | ((unsigned)i2 << 16);
}

// ---------------------------------------------------------------------------
// Phase 2: encoder MLP. One block per graph; stages h4 from tmp into LDS;
// each thread runs 3 solo edge-MLPs sequentially (round-12 verbatim path,
// sum ((e0+e1)+e2)). Overwrites tmp with (he0, he1, |he|^2, 0).
// ---------------------------------------------------------------------------
__global__ __launch_bounds__(256) void k_mlp_enc(
    const float*  __restrict__ ew1, const float* __restrict__ eb1,
    const float*  __restrict__ ew2, const float* __restrict__ eb2,
    const float*  __restrict__ ew3, const float* __restrict__ eb3,
    float4*       __restrict__ tmp,
    const unsigned int* __restrict__ idx)
{
    __shared__ float4 s_h4[NN];

    const int n = threadIdx.x;
    const int b = blockIdx.x;

    float4 h4 = tmp[b * NN + n];
    s_h4[n] = h4;
    __syncthreads();

    float h0 = h4.x, h1 = h4.y, h2 = h4.z, h3 = h4.w;
    unsigned pi = idx[b * NN + n];
    int j0 = pi & 255, j1 = (pi >> 8) & 255, j2i = (pi >> 16) & 255;

    float ms0 = 0.0f, ms1 = 0.0f;
#pragma unroll 1
    for (int k = 0; k < NK; ++k) {
        int j = (k == 0) ? j0 : (k == 1 ? j1 : j2i);

        f32x16 Aa = ldw16(eb1), Ab = ldw16(eb1 + 16);
        ROW1(h0, ew1 + 0 * BIG, Aa, Ab);
        ROW1(h1, ew1 + 1 * BIG, Aa, Ab);
        ROW1(h2, ew1 + 2 * BIG, Aa, Ab);
        ROW1(h3, ew1 + 3 * BIG, Aa, Ab);
        float4 a2v = s_h4[j];
        float p20 = a2v.x - h0, p21 = a2v.y - h1;
        float p22 = a2v.z - h2, p23 = a2v.w - h3;
        ROW1(p20, ew1 + 4 * BIG, Aa, Ab);
        ROW1(p21, ew1 + 5 * BIG, Aa, Ab);
        ROW1(p22, ew1 + 6 * BIG, Aa, Ab);
        ROW1(p23, ew1 + 7 * BIG, Aa, Ab);
        Aa = relu16(Aa); Ab = relu16(Ab);

        float o0e2 = eb3[0], o1e2 = eb3[1];
        { L2S(ew2, eb2, 0,  Aa, Ab, QS0); L3ES(0,  QS0); }
        { L2S(ew2, eb2, 16, Aa, Ab, QS1); L3ES(16, QS1); }
        ms0 += fmaxf(o0e2, 0.0f);
        ms1 += fmaxf(o1e2, 0.0f);
    }
    float he0 = ms0 / 3.0f, he1 = ms1 / 3.0f;
    float sqe = he0 * he0 + he1 * he1;
    tmp[b * NN + n] = make_float4(he0, he1, sqe, 0.0f);
}

// ---------------------------------------------------------------------------
// Phase 3: decoder kNN. Reads (he0,he1,sqe) from tmp, writes packed idx.
// ---------------------------------------------------------------------------
__global__ __launch_bounds__(256) void k_knn_dec(
    const float4* __restrict__ tmp,
    unsigned int* __restrict__ idx)
{
    __shared__ float2 s_he2[NN];
    __shared__ float  s_sq2[NN];

    const int n = threadIdx.x;
    const int b = blockIdx.x;

    float4 t = tmp[b * NN + n];
    float he0 = t.x, he1 = t.y, sqe = t.z;
    s_he2[n] = make_float2(he0, he1);
    s_sq2[n] = sqe;
    __syncthreads();

    float d0 = FLT_BIG, d1 = FLT_BIG, d2 = FLT_BIG;
    int   i0 = 0, i1 = 0, i2 = 0;
    for (int m = 0; m < NN; ++m) {
        float2 a = s_he2[m];
        float dot = he0 * a.x + he1 * a.y;
        float dd = (sqe + s_sq2[m]) - 2.0f * dot;
        KNN_UPDATE(dd, m);
    }
    idx[b * NN + n] = (unsigned)i0 | ((unsigned)i1 << 8) | ((unsigned)i2 << 16);
}

// ---------------------------------------------------------------------------
// Phase 4: decoder MLP. Stages he2 from tmp into LDS (all reads via LDS after
// barrier), runs 3 solo edge-MLPs, overwrites tmp with the final output.
// ---------------------------------------------------------------------------
__global__ __launch_bounds__(256) void k_mlp_dec(
    const float*  __restrict__ dw1, const float* __restrict__ db1,
    const float*  __restrict__ dw2, const float* __restrict__ db2,
    const float*  __restrict__ dw3, const float* __restrict__ db3,
    float4*       __restrict__ tmp,
    const unsigned int* __restrict__ idx)
{
    __shared__ float2 s_he2[NN];

    const int n = threadIdx.x;
    const int b = blockIdx.x;

    float4 t = tmp[b * NN + n];
    float he0 = t.x, he1 = t.y;
    s_he2[n] = make_float2(he0, he1);
    __syncthreads();

    unsigned pi = idx[b * NN + n];
    int j0 = pi & 255, j1 = (pi >> 8) & 255, j2i = (pi >> 16) & 255;

    f32x4v osum = {0.0f, 0.0f, 0.0f, 0.0f};
#pragma unroll 1
    for (int k = 0; k < NK; ++k) {
        int j = (k == 0) ? j0 : (k == 1 ? j1 : j2i);

        f32x16 Ba = ldw16(db1), Bb = ldw16(db1 + 16);
        ROW1(he0, dw1 + 0 * BIG, Ba, Bb);
        ROW1(he1, dw1 + 1 * BIG, Ba, Bb);
        float2 a2v = s_he2[j];
        float p20 = a2v.x - he0, p21 = a2v.y - he1;
        ROW1(p20, dw1 + 2 * BIG, Ba, Bb);
        ROW1(p21, dw1 + 3 * BIG, Ba, Bb);
        Ba = relu16(Ba); Bb = relu16(Bb);

        f32x4v ove2 = ldw4(db3);
        { L2S(dw2, db2, 0,  Ba, Bb, QF0); L3DS(0,  QF0); }
        { L2S(dw2, db2, 16, Ba, Bb, QF1); L3DS(16, QF1); }
        osum += ove2;
    }
    float4 ov;
    ov.x = osum[0] / 3.0f; ov.y = osum[1] / 3.0f;
    ov.z = osum[2] / 3.0f; ov.w = osum[3] / 3.0f;
    tmp[b * NN + n] = ov;
}

// ---------------------------------------------------------------------------
extern "C" void kernel_launch(void* const* d_in, const int* in_sizes, int n_in,
                              void* d_out, int out_size, void* d_ws, size_t ws_size,
                              hipStream_t stream) {
    const float* x   = (const float*)d_in[0];
    const float* gmm = (const float*)d_in[1];
    const float* bta = (const float*)d_in[2];
    const float* ew1 = (const float*)d_in[3];
    const float* eb1 = (const float*)d_in[4];
    const float* ew2 = (const float*)d_in[5];
    const float* eb2 = (const float*)d_in[6];
    const float* ew3 = (const float*)d_in[7];
    const float* eb3 = (const float*)d_in[8];
    const float* dw1 = (const float*)d_in[9];
    const float* db1 = (const float*)d_in[10];
    const float* dw2 = (const float*)d_in[11];
    const float* db2 = (const float*)d_in[12];
    const float* dw3 = (const float*)d_in[13];
    const float* db3 = (const float*)d_in[14];

    double*       ws   = (double*)d_ws;
    unsigned int* idxb = (unsigned int*)((char*)d_ws + 64);   // 1 MB packed idx
    float4*       tmp  = (float4*)d_out;

    hipLaunchKernelGGL(k_zero_ws, dim3(1), dim3(64), 0, stream, ws);
    hipLaunchKernelGGL(k_bn_reduce, dim3(256), dim3(256), 0, stream,
                       (const float4*)x, ws);
    hipLaunchKernelGGL(k_knn_enc, dim3(NB), dim3(256), 0, stream,
                       x, gmm, bta, ws, tmp, idxb);
    hipLaunchKernelGGL(k_mlp_enc, dim3(NB), dim3(256), 0, stream,
                       ew1, eb1, ew2, eb2, ew3, eb3, tmp, idxb);
    hipLaunchKernelGGL(k_knn_dec, dim3(NB), dim3(256), 0, stream,
                       tmp, idxb);
    hipLaunchKernelGGL(k_mlp_dec, dim3(NB), dim3(256), 0, stream,
                       dw1, db1, dw2, db2, dw3, db3, tmp, idxb);
}

// Round 14
// 236.072 us; speedup vs baseline: 1.3338x; 1.3338x over previous
//
#include <hip/hip_runtime.h>
#include <math.h>

#define NB  1024
#define NN  256
#define NF  4
#define NK  3
#define BIG 32
#define HID 2
#define BN_EPS 1e-5f
#define FLT_BIG 3.402823466e38f

typedef float f32x16 __attribute__((ext_vector_type(16)));
typedef float f32x4v __attribute__((ext_vector_type(4)));

static __device__ __forceinline__ f32x16 splat16(float s) {
    f32x16 v;
#pragma unroll
    for (int k = 0; k < 16; ++k) v[k] = s;
    return v;
}
static __device__ __forceinline__ f32x16 relu16(f32x16 v) {
    return __builtin_elementwise_max(v, splat16(0.0f));
}
static __device__ __forceinline__ f32x16 ldw16(const float* __restrict__ p) {
    return *(const f32x16*)p;   // uniform addr -> s_load_dwordx16
}
static __device__ __forceinline__ f32x4v ldw4(const float* __restrict__ p) {
    return *(const f32x4v*)p;
}
static __device__ __forceinline__ f32x4v splat4(float s) {
    f32x4v v; v[0] = s; v[1] = s; v[2] = s; v[3] = s; return v;
}

#define ROW1(s, base, Aa, Ab) { \
    f32x16 w0_ = ldw16(base); f32x16 w1_ = ldw16((base) + 16); \
    f32x16 sv_ = splat16(s); Aa += sv_ * w0_; Ab += sv_ * w1_; }

#define L2S(wbase, bbase, COFF, INa, INb, Q) \
    f32x16 Q = ldw16((bbase) + (COFF)); \
    _Pragma("unroll") \
    for (int i_ = 0; i_ < 16; i_++) { \
        f32x16 w_ = ldw16((wbase) + i_ * BIG + (COFF)); \
        Q += splat16(INa[i_]) * w_; } \
    _Pragma("unroll") \
    for (int i_ = 0; i_ < 16; i_++) { \
        f32x16 w_ = ldw16((wbase) + (16 + i_) * BIG + (COFF)); \
        Q += splat16(INb[i_]) * w_; } \
    Q = relu16(Q);

#define L3ES(COFF, Q) { \
    f32x16 wA_ = ldw16(ew3 + (COFF) * 2); \
    f32x16 wB_ = ldw16(ew3 + (COFF) * 2 + 16); \
    _Pragma("unroll") \
    for (int i_ = 0; i_ < 8; i_++) { \
        o0e2 += Q[i_] * wA_[2 * i_]; o1e2 += Q[i_] * wA_[2 * i_ + 1]; } \
    _Pragma("unroll") \
    for (int i_ = 0; i_ < 8; i_++) { \
        o0e2 += Q[8 + i_] * wB_[2 * i_]; o1e2 += Q[8 + i_] * wB_[2 * i_ + 1]; } }

#define L3DS(COFF, Q) { \
    _Pragma("unroll") \
    for (int i_ = 0; i_ < 16; i_++) { \
        f32x4v w_ = ldw4(dw3 + ((COFF) + i_) * 4); \
        ove2 += splat4(Q[i_]) * w_; } }

// top-3 streaming insert: strict <, fmed3 distances, cndmask indices.
#define KNN_UPDATE(d, m) { \
    bool c0 = (d) < d0, c1 = (d) < d1, c2 = (d) < d2; \
    i2 = c1 ? i1 : (c2 ? (m) : i2); \
    i1 = c0 ? i0 : (c1 ? (m) : i1); \
    i0 = c0 ? (m) : i0; \
    d2 = __builtin_amdgcn_fmed3f((d), d1, d2); \
    d1 = __builtin_amdgcn_fmed3f((d), d0, d1); \
    d0 = fminf((d), d0); }

// ---------------------------------------------------------------------------
__global__ void k_zero_ws(double* ws) {
    if (threadIdx.x < 8) ws[threadIdx.x] = 0.0;
}

__global__ __launch_bounds__(256) void k_bn_reduce(const float4* __restrict__ x,
                                                   double* __restrict__ ws) {
    int tid = blockIdx.x * 256 + threadIdx.x;
    double s[8] = {0, 0, 0, 0, 0, 0, 0, 0};
    for (int r = tid; r < NB * NN; r += 256 * 256) {
        float4 v = x[r];
        s[0] += v.x; s[1] += v.y; s[2] += v.z; s[3] += v.w;
        s[4] += (double)v.x * v.x; s[5] += (double)v.y * v.y;
        s[6] += (double)v.z * v.z; s[7] += (double)v.w * v.w;
    }
#pragma unroll
    for (int off = 32; off > 0; off >>= 1) {
#pragma unroll
        for (int i = 0; i < 8; i++) s[i] += __shfl_down(s[i], off);
    }
    __shared__ double red[4][8];
    int w = threadIdx.x >> 6, lane = threadIdx.x & 63;
    if (lane == 0) {
#pragma unroll
        for (int i = 0; i < 8; i++) red[w][i] = s[i];
    }
    __syncthreads();
    if (threadIdx.x == 0) {
#pragma unroll
        for (int i = 0; i < 8; i++) {
            double t = red[0][i] + red[1][i] + red[2][i] + red[3][i];
            atomicAdd(&ws[i], t);
        }
    }
}

// ---------------------------------------------------------------------------
// Phase 1: BN-normalize + encoder kNN. One block per graph. Writes h4 to tmp
// and packed top-3 indices (u32: i0 | i1<<8 | i2<<16) to idx.
// ---------------------------------------------------------------------------
__global__ __launch_bounds__(256) void k_knn_enc(
    const float*  __restrict__ x,
    const float*  __restrict__ gmm, const float* __restrict__ bta,
    const double* __restrict__ bnstat,
    float4*       __restrict__ tmp,
    unsigned int* __restrict__ idx)
{
    __shared__ float4 s_h4[NN];
    __shared__ float  s_sq[NN];

    const int n = threadIdx.x;
    const int b = blockIdx.x;

    const double cnt = (double)(NB * NN);
    float mu[NF], rstd[NF];
#pragma unroll
    for (int f = 0; f < NF; f++) {
        double m   = bnstat[f] / cnt;
        double var = bnstat[4 + f] / cnt - m * m;
        mu[f]   = (float)m;
        rstd[f] = 1.0f / sqrtf((float)var + BN_EPS);
    }

    float4 xv = ((const float4*)x)[b * NN + n];
    float h0 = (xv.x - mu[0]) * rstd[0] * gmm[0] + bta[0];
    float h1 = (xv.y - mu[1]) * rstd[1] * gmm[1] + bta[1];
    float h2 = (xv.z - mu[2]) * rstd[2] * gmm[2] + bta[2];
    float h3 = (xv.w - mu[3]) * rstd[3] * gmm[3] + bta[3];
    float4 h4 = make_float4(h0, h1, h2, h3);
    s_h4[n] = h4;
    float sq = h0 * h0 + h1 * h1 + h2 * h2 + h3 * h3;
    s_sq[n] = sq;
    tmp[b * NN + n] = h4;
    __syncthreads();

    float d0 = FLT_BIG, d1 = FLT_BIG, d2 = FLT_BIG;
    int   i0 = 0, i1 = 0, i2 = 0;
    for (int m = 0; m < NN; ++m) {
        float4 a = s_h4[m];
        float dot = h0 * a.x + h1 * a.y + h2 * a.z + h3 * a.w;
        float dd = (sq + s_sq[m]) - 2.0f * dot;
        KNN_UPDATE(dd, m);
    }
    idx[b * NN + n] = (unsigned)i0 | ((unsigned)i1 << 8) | ((unsigned)i2 << 16);
}

// ---------------------------------------------------------------------------
// Phase 2: encoder MLP, EDGE-parallel. Block (b,k) handles edge k of all 256
// nodes of graph b (786k threads total -> ~6 waves/SIMD latency hiding).
// h4(n), h4(j) read straight from tmp (4KB/graph, L2-hot). Solo path verbatim.
// ---------------------------------------------------------------------------
__global__ __launch_bounds__(256) void k_mlp_enc_edge(
    const float*  __restrict__ ew1, const float* __restrict__ eb1,
    const float*  __restrict__ ew2, const float* __restrict__ eb2,
    const float*  __restrict__ ew3, const float* __restrict__ eb3,
    const float4* __restrict__ tmp,
    const unsigned int* __restrict__ idx,
    float2*       __restrict__ pe)
{
    const int n = threadIdx.x;
    const int b = blockIdx.x;
    const int k = blockIdx.y;     // 0..2, uniform

    float4 h4 = tmp[b * NN + n];
    float h0 = h4.x, h1 = h4.y, h2 = h4.z, h3 = h4.w;
    unsigned pi = idx[b * NN + n];
    int j = (pi >> (8 * k)) & 255;
    float4 aj = tmp[b * NN + j];

    f32x16 Aa = ldw16(eb1), Ab = ldw16(eb1 + 16);
    ROW1(h0, ew1 + 0 * BIG, Aa, Ab);
    ROW1(h1, ew1 + 1 * BIG, Aa, Ab);
    ROW1(h2, ew1 + 2 * BIG, Aa, Ab);
    ROW1(h3, ew1 + 3 * BIG, Aa, Ab);
    float p20 = aj.x - h0, p21 = aj.y - h1;
    float p22 = aj.z - h2, p23 = aj.w - h3;
    ROW1(p20, ew1 + 4 * BIG, Aa, Ab);
    ROW1(p21, ew1 + 5 * BIG, Aa, Ab);
    ROW1(p22, ew1 + 6 * BIG, Aa, Ab);
    ROW1(p23, ew1 + 7 * BIG, Aa, Ab);
    Aa = relu16(Aa); Ab = relu16(Ab);

    float o0e2 = eb3[0], o1e2 = eb3[1];
    { L2S(ew2, eb2, 0,  Aa, Ab, QS0); L3ES(0,  QS0); }
    { L2S(ew2, eb2, 16, Aa, Ab, QS1); L3ES(16, QS1); }
    pe[(k * NB + b) * NN + n] = make_float2(fmaxf(o0e2, 0.0f), fmaxf(o1e2, 0.0f));
}

// ---------------------------------------------------------------------------
// Phase 3: combine encoder partials ((e0+e1)+e2)/3 + decoder kNN.
// Writes (he0,he1,sqe) to tmp and packed idx.
// ---------------------------------------------------------------------------
__global__ __launch_bounds__(256) void k_knn_dec(
    const float2* __restrict__ pe,
    float4*       __restrict__ tmp,
    unsigned int* __restrict__ idx)
{
    __shared__ float2 s_he2[NN];
    __shared__ float  s_sq2[NN];

    const int n = threadIdx.x;
    const int b = blockIdx.x;

    float2 p0 = pe[(0 * NB + b) * NN + n];
    float2 p1 = pe[(1 * NB + b) * NN + n];
    float2 p2 = pe[(2 * NB + b) * NN + n];
    float ms0 = (p0.x + p1.x) + p2.x;     // round-13 order
    float ms1 = (p0.y + p1.y) + p2.y;
    float he0 = ms0 / 3.0f, he1 = ms1 / 3.0f;
    float sqe = he0 * he0 + he1 * he1;
    s_he2[n] = make_float2(he0, he1);
    s_sq2[n] = sqe;
    tmp[b * NN + n] = make_float4(he0, he1, sqe, 0.0f);
    __syncthreads();

    float d0 = FLT_BIG, d1 = FLT_BIG, d2 = FLT_BIG;
    int   i0 = 0, i1 = 0, i2 = 0;
    for (int m = 0; m < NN; ++m) {
        float2 a = s_he2[m];
        float dot = he0 * a.x + he1 * a.y;
        float dd = (sqe + s_sq2[m]) - 2.0f * dot;
        KNN_UPDATE(dd, m);
    }
    idx[b * NN + n] = (unsigned)i0 | ((unsigned)i1 << 8) | ((unsigned)i2 << 16);
}

// ---------------------------------------------------------------------------
// Phase 4: decoder MLP, EDGE-parallel. Same structure as phase 2.
// ---------------------------------------------------------------------------
__global__ __launch_bounds__(256) void k_mlp_dec_edge(
    const float*  __restrict__ dw1, const float* __restrict__ db1,
    const float*  __restrict__ dw2, const float* __restrict__ db2,
    const float*  __restrict__ dw3, const float* __restrict__ db3,
    const float4* __restrict__ tmp,
    const unsigned int* __restrict__ idx,
    float4*       __restrict__ pd)
{
    const int n = threadIdx.x;
    const int b = blockIdx.x;
    const int k = blockIdx.y;

    float4 t = tmp[b * NN + n];
    float he0 = t.x, he1 = t.y;
    unsigned pi = idx[b * NN + n];
    int j = (pi >> (8 * k)) & 255;
    float4 tj = tmp[b * NN + j];

    f32x16 Ba = ldw16(db1), Bb = ldw16(db1 + 16);
    ROW1(he0, dw1 + 0 * BIG, Ba, Bb);
    ROW1(he1, dw1 + 1 * BIG, Ba, Bb);
    float p20 = tj.x - he0, p21 = tj.y - he1;
    ROW1(p20, dw1 + 2 * BIG, Ba, Bb);
    ROW1(p21, dw1 + 3 * BIG, Ba, Bb);
    Ba = relu16(Ba); Bb = relu16(Bb);

    f32x4v ove2 = ldw4(db3);
    { L2S(dw2, db2, 0,  Ba, Bb, QF0); L3DS(0,  QF0); }
    { L2S(dw2, db2, 16, Ba, Bb, QF1); L3DS(16, QF1); }
    pd[(k * NB + b) * NN + n] = make_float4(ove2[0], ove2[1], ove2[2], ove2[3]);
}

// ---------------------------------------------------------------------------
// Phase 5: combine decoder partials -> final output.
// ---------------------------------------------------------------------------
__global__ __launch_bounds__(256) void k_comb_dec(
    const float4* __restrict__ pd,
    float4*       __restrict__ out)
{
    int g = blockIdx.x * 256 + threadIdx.x;   // [0, NB*NN)
    float4 p0 = pd[0 * NB * NN + g];
    float4 p1 = pd[1 * NB * NN + g];
    float4 p2 = pd[2 * NB * NN + g];
    float4 ov;                                 // round-13 order
    ov.x = ((p0.x + p1.x) + p2.x) / 3.0f;
    ov.y = ((p0.y + p1.y) + p2.y) / 3.0f;
    ov.z = ((p0.z + p1.z) + p2.z) / 3.0f;
    ov.w = ((p0.w + p1.w) + p2.w) / 3.0f;
    out[g] = ov;
}

// ---------------------------------------------------------------------------
extern "C" void kernel_launch(void* const* d_in, const int* in_sizes, int n_in,
                              void* d_out, int out_size, void* d_ws, size_t ws_size,
                              hipStream_t stream) {
    const float* x   = (const float*)d_in[0];
    const float* gmm = (const float*)d_in[1];
    const float* bta = (const float*)d_in[2];
    const float* ew1 = (const float*)d_in[3];
    const float* eb1 = (const float*)d_in[4];
    const float* ew2 = (const float*)d_in[5];
    const float* eb2 = (const float*)d_in[6];
    const float* ew3 = (const float*)d_in[7];
    const float* eb3 = (const float*)d_in[8];
    const float* dw1 = (const float*)d_in[9];
    const float* db1 = (const float*)d_in[10];
    const float* dw2 = (const float*)d_in[11];
    const float* db2 = (const float*)d_in[12];
    const float* dw3 = (const float*)d_in[13];
    const float* db3 = (const float*)d_in[14];

    double*       ws   = (double*)d_ws;
    unsigned int* idxb = (unsigned int*)((char*)d_ws + 64);            // 1 MB
    char*         pbuf = (char*)d_ws + 64 + (size_t)NB * NN * 4;       // 12.6 MB
    float2*       pe   = (float2*)pbuf;
    float4*       pd   = (float4*)pbuf;
    float4*       tmp  = (float4*)d_out;

    hipLaunchKernelGGL(k_zero_ws, dim3(1), dim3(64), 0, stream, ws);
    hipLaunchKernelGGL(k_bn_reduce, dim3(256), dim3(256), 0, stream,
                       (const float4*)x, ws);
    hipLaunchKernelGGL(k_knn_enc, dim3(NB), dim3(256), 0, stream,
                       x, gmm, bta, ws, tmp, idxb);
    hipLaunchKernelGGL(k_mlp_enc_edge, dim3(NB, NK), dim3(256), 0, stream,
                       ew1, eb1, ew2, eb2, ew3, eb3, tmp, idxb, pe);
    hipLaunchKernelGGL(k_knn_dec, dim3(NB), dim3(256), 0, stream,
                       pe, tmp, idxb);
    hipLaunchKernelGGL(k_mlp_dec_edge, dim3(NB, NK), dim3(256), 0, stream,
                       dw1, db1, dw2, db2, dw3, db3, tmp, idxb, pd);
    hipLaunchKernelGGL(k_comb_dec, dim3(NB), dim3(256), 0, stream,
                       pd, tmp);
}

// Round 15
// 235.391 us; speedup vs baseline: 1.3377x; 1.0029x over previous
//
#include <hip/hip_runtime.h>
#include <math.h>

#define NB  1024
#define NN  256
#define NF  4
#define NK  3
#define BIG 32
#define HID 2
#define BN_EPS 1e-5f
#define FLT_BIG 3.402823466e38f

typedef float f32x16 __attribute__((ext_vector_type(16)));
typedef float f32x4v __attribute__((ext_vector_type(4)));

static __device__ __forceinline__ f32x16 splat16(float s) {
    f32x16 v;
#pragma unroll
    for (int k = 0; k < 16; ++k) v[k] = s;
    return v;
}
static __device__ __forceinline__ f32x16 relu16(f32x16 v) {
    return __builtin_elementwise_max(v, splat16(0.0f));
}
static __device__ __forceinline__ f32x16 ldw16(const float* __restrict__ p) {
    return *(const f32x16*)p;   // uniform addr -> s_load_dwordx16
}
static __device__ __forceinline__ f32x4v ldw4(const float* __restrict__ p) {
    return *(const f32x4v*)p;
}
static __device__ __forceinline__ f32x4v splat4(float s) {
    f32x4v v; v[0] = s; v[1] = s; v[2] = s; v[3] = s; return v;
}

#define ROW1(s, base, Aa, Ab) { \
    f32x16 w0_ = ldw16(base); f32x16 w1_ = ldw16((base) + 16); \
    f32x16 sv_ = splat16(s); Aa += sv_ * w0_; Ab += sv_ * w1_; }

#define L2S(wbase, bbase, COFF, INa, INb, Q) \
    f32x16 Q = ldw16((bbase) + (COFF)); \
    _Pragma("unroll") \
    for (int i_ = 0; i_ < 16; i_++) { \
        f32x16 w_ = ldw16((wbase) + i_ * BIG + (COFF)); \
        Q += splat16(INa[i_]) * w_; } \
    _Pragma("unroll") \
    for (int i_ = 0; i_ < 16; i_++) { \
        f32x16 w_ = ldw16((wbase) + (16 + i_) * BIG + (COFF)); \
        Q += splat16(INb[i_]) * w_; } \
    Q = relu16(Q);

#define L3ES(COFF, Q) { \
    f32x16 wA_ = ldw16(ew3 + (COFF) * 2); \
    f32x16 wB_ = ldw16(ew3 + (COFF) * 2 + 16); \
    _Pragma("unroll") \
    for (int i_ = 0; i_ < 8; i_++) { \
        o0e2 += Q[i_] * wA_[2 * i_]; o1e2 += Q[i_] * wA_[2 * i_ + 1]; } \
    _Pragma("unroll") \
    for (int i_ = 0; i_ < 8; i_++) { \
        o0e2 += Q[8 + i_] * wB_[2 * i_]; o1e2 += Q[8 + i_] * wB_[2 * i_ + 1]; } }

#define L3DS(COFF, Q) { \
    _Pragma("unroll") \
    for (int i_ = 0; i_ < 16; i_++) { \
        f32x4v w_ = ldw4(dw3 + ((COFF) + i_) * 4); \
        ove2 += splat4(Q[i_]) * w_; } }

// top-3 streaming insert on named state (strict <, fmed3 distances).
#define KNN_UPD(d, m, D0, D1, D2, I0, I1, I2) { \
    bool c0 = (d) < D0, c1 = (d) < D1, c2 = (d) < D2; \
    I2 = c1 ? I1 : (c2 ? (m) : I2); \
    I1 = c0 ? I0 : (c1 ? (m) : I1); \
    I0 = c0 ? (m) : I0; \
    D2 = __builtin_amdgcn_fmed3f((d), D1, D2); \
    D1 = __builtin_amdgcn_fmed3f((d), D0, D1); \
    D0 = fminf((d), D0); }

// ---------------------------------------------------------------------------
__global__ void k_zero_ws(double* ws) {
    if (threadIdx.x < 8) ws[threadIdx.x] = 0.0;
}

__global__ __launch_bounds__(256) void k_bn_reduce(const float4* __restrict__ x,
                                                   double* __restrict__ ws) {
    int tid = blockIdx.x * 256 + threadIdx.x;
    double s[8] = {0, 0, 0, 0, 0, 0, 0, 0};
    for (int r = tid; r < NB * NN; r += 256 * 256) {
        float4 v = x[r];
        s[0] += v.x; s[1] += v.y; s[2] += v.z; s[3] += v.w;
        s[4] += (double)v.x * v.x; s[5] += (double)v.y * v.y;
        s[6] += (double)v.z * v.z; s[7] += (double)v.w * v.w;
    }
#pragma unroll
    for (int off = 32; off > 0; off >>= 1) {
#pragma unroll
        for (int i = 0; i < 8; i++) s[i] += __shfl_down(s[i], off);
    }
    __shared__ double red[4][8];
    int w = threadIdx.x >> 6, lane = threadIdx.x & 63;
    if (lane == 0) {
#pragma unroll
        for (int i = 0; i < 8; i++) red[w][i] = s[i];
    }
    __syncthreads();
    if (threadIdx.x == 0) {
#pragma unroll
        for (int i = 0; i < 8; i++) {
            double t = red[0][i] + red[1][i] + red[2][i] + red[3][i];
            atomicAdd(&ws[i], t);
        }
    }
}

// ---------------------------------------------------------------------------
// Phase 1: BN-normalize + encoder kNN. 512 threads = 2 per node. Each half
// scans 128 candidates as two independent 64-streams (ILP), merges streams,
// half B publishes its top-3, half A merges (stable segment merge) and
// writes packed idx. h4 written to tmp.
// ---------------------------------------------------------------------------
__global__ __launch_bounds__(512) void k_knn_enc(
    const float*  __restrict__ x,
    const float*  __restrict__ gmm, const float* __restrict__ bta,
    const double* __restrict__ bnstat,
    float4*       __restrict__ tmp,
    unsigned int* __restrict__ idx)
{
    __shared__ float4 s_h4[NN];
    __shared__ float  s_sq[NN];
    __shared__ float4 s_bd[NN];
    __shared__ int4   s_bi[NN];

    const int tid  = threadIdx.x;
    const int n    = tid & (NN - 1);
    const int half = tid >> 8;
    const int b    = blockIdx.x;

    if (half == 0) {
        const double cnt = (double)(NB * NN);
        float mu[NF], rstd[NF];
#pragma unroll
        for (int f = 0; f < NF; f++) {
            double m   = bnstat[f] / cnt;
            double var = bnstat[4 + f] / cnt - m * m;
            mu[f]   = (float)m;
            rstd[f] = 1.0f / sqrtf((float)var + BN_EPS);
        }
        float4 xv = ((const float4*)x)[b * NN + n];
        float t0 = (xv.x - mu[0]) * rstd[0] * gmm[0] + bta[0];
        float t1 = (xv.y - mu[1]) * rstd[1] * gmm[1] + bta[1];
        float t2 = (xv.z - mu[2]) * rstd[2] * gmm[2] + bta[2];
        float t3 = (xv.w - mu[3]) * rstd[3] * gmm[3] + bta[3];
        float4 h4 = make_float4(t0, t1, t2, t3);
        s_h4[n] = h4;
        s_sq[n] = t0 * t0 + t1 * t1 + t2 * t2 + t3 * t3;
        tmp[b * NN + n] = h4;
    }
    __syncthreads();

    float4 hv = s_h4[n];
    float h0 = hv.x, h1 = hv.y, h2 = hv.z, h3 = hv.w;
    float sq = s_sq[n];

    // two independent 64-streams per half
    const int beg = half << 7;
    float ad0 = FLT_BIG, ad1 = FLT_BIG, ad2 = FLT_BIG;
    int   ai0 = 0, ai1 = 0, ai2 = 0;
    float bd0 = FLT_BIG, bd1 = FLT_BIG, bd2 = FLT_BIG;
    int   bi0 = 0, bi1 = 0, bi2 = 0;
    for (int m = beg; m < beg + 64; ++m) {
        int m2 = m + 64;
        float4 a = s_h4[m];
        float dotA = h0 * a.x + h1 * a.y + h2 * a.z + h3 * a.w;
        float dA = (sq + s_sq[m]) - 2.0f * dotA;
        float4 c = s_h4[m2];
        float dotB = h0 * c.x + h1 * c.y + h2 * c.z + h3 * c.w;
        float dB = (sq + s_sq[m2]) - 2.0f * dotB;
        KNN_UPD(dA, m,  ad0, ad1, ad2, ai0, ai1, ai2);
        KNN_UPD(dB, m2, bd0, bd1, bd2, bi0, bi1, bi2);
    }
    // merge stream B (indices all > stream A's) — stable segment merge
    KNN_UPD(bd0, bi0, ad0, ad1, ad2, ai0, ai1, ai2);
    KNN_UPD(bd1, bi1, ad0, ad1, ad2, ai0, ai1, ai2);
    KNN_UPD(bd2, bi2, ad0, ad1, ad2, ai0, ai1, ai2);

    if (half == 1) {
        s_bd[n] = make_float4(ad0, ad1, ad2, 0.0f);
        s_bi[n] = make_int4(ai0, ai1, ai2, 0);
    }
    __syncthreads();
    if (half == 0) {
        float4 pd = s_bd[n]; int4 pi = s_bi[n];
        KNN_UPD(pd.x, pi.x, ad0, ad1, ad2, ai0, ai1, ai2);
        KNN_UPD(pd.y, pi.y, ad0, ad1, ad2, ai0, ai1, ai2);
        KNN_UPD(pd.z, pi.z, ad0, ad1, ad2, ai0, ai1, ai2);
        idx[b * NN + n] = (unsigned)ai0 | ((unsigned)ai1 << 8) | ((unsigned)ai2 << 16);
    }
}

// ---------------------------------------------------------------------------
// Phase 2: encoder MLP, EDGE-parallel (verbatim from round 14).
// ---------------------------------------------------------------------------
__global__ __launch_bounds__(256) void k_mlp_enc_edge(
    const float*  __restrict__ ew1, const float* __restrict__ eb1,
    const float*  __restrict__ ew2, const float* __restrict__ eb2,
    const float*  __restrict__ ew3, const float* __restrict__ eb3,
    const float4* __restrict__ tmp,
    const unsigned int* __restrict__ idx,
    float2*       __restrict__ pe)
{
    const int n = threadIdx.x;
    const int b = blockIdx.x;
    const int k = blockIdx.y;     // 0..2, uniform

    float4 h4 = tmp[b * NN + n];
    float h0 = h4.x, h1 = h4.y, h2 = h4.z, h3 = h4.w;
    unsigned pi = idx[b * NN + n];
    int j = (pi >> (8 * k)) & 255;
    float4 aj = tmp[b * NN + j];

    f32x16 Aa = ldw16(eb1), Ab = ldw16(eb1 + 16);
    ROW1(h0, ew1 + 0 * BIG, Aa, Ab);
    ROW1(h1, ew1 + 1 * BIG, Aa, Ab);
    ROW1(h2, ew1 + 2 * BIG, Aa, Ab);
    ROW1(h3, ew1 + 3 * BIG, Aa, Ab);
    float p20 = aj.x - h0, p21 = aj.y - h1;
    float p22 = aj.z - h2, p23 = aj.w - h3;
    ROW1(p20, ew1 + 4 * BIG, Aa, Ab);
    ROW1(p21, ew1 + 5 * BIG, Aa, Ab);
    ROW1(p22, ew1 + 6 * BIG, Aa, Ab);
    ROW1(p23, ew1 + 7 * BIG, Aa, Ab);
    Aa = relu16(Aa); Ab = relu16(Ab);

    float o0e2 = eb3[0], o1e2 = eb3[1];
    { L2S(ew2, eb2, 0,  Aa, Ab, QS0); L3ES(0,  QS0); }
    { L2S(ew2, eb2, 16, Aa, Ab, QS1); L3ES(16, QS1); }
    pe[(k * NB + b) * NN + n] = make_float2(fmaxf(o0e2, 0.0f), fmaxf(o1e2, 0.0f));
}

// ---------------------------------------------------------------------------
// Phase 3: combine encoder partials + decoder kNN. 512 threads = 2 per node,
// same half-scan/merge structure as phase 1.
// ---------------------------------------------------------------------------
__global__ __launch_bounds__(512) void k_knn_dec(
    const float2* __restrict__ pe,
    float4*       __restrict__ tmp,
    unsigned int* __restrict__ idx)
{
    __shared__ float2 s_he2[NN];
    __shared__ float  s_sq2[NN];
    __shared__ float4 s_bd[NN];
    __shared__ int4   s_bi[NN];

    const int tid  = threadIdx.x;
    const int n    = tid & (NN - 1);
    const int half = tid >> 8;
    const int b    = blockIdx.x;

    if (half == 0) {
        float2 p0 = pe[(0 * NB + b) * NN + n];
        float2 p1 = pe[(1 * NB + b) * NN + n];
        float2 p2 = pe[(2 * NB + b) * NN + n];
        float ms0 = (p0.x + p1.x) + p2.x;     // round-14 order
        float ms1 = (p0.y + p1.y) + p2.y;
        float he0 = ms0 / 3.0f, he1 = ms1 / 3.0f;
        float sqe = he0 * he0 + he1 * he1;
        s_he2[n] = make_float2(he0, he1);
        s_sq2[n] = sqe;
        tmp[b * NN + n] = make_float4(he0, he1, sqe, 0.0f);
    }
    __syncthreads();

    float2 hev = s_he2[n];
    float he0 = hev.x, he1 = hev.y;
    float sqe = s_sq2[n];

    const int beg = half << 7;
    float ad0 = FLT_BIG, ad1 = FLT_BIG, ad2 = FLT_BIG;
    int   ai0 = 0, ai1 = 0, ai2 = 0;
    float bd0 = FLT_BIG, bd1 = FLT_BIG, bd2 = FLT_BIG;
    int   bi0 = 0, bi1 = 0, bi2 = 0;
    for (int m = beg; m < beg + 64; ++m) {
        int m2 = m + 64;
        float2 a = s_he2[m];
        float dA = (sqe + s_sq2[m]) - 2.0f * (he0 * a.x + he1 * a.y);
        float2 c = s_he2[m2];
        float dB = (sqe + s_sq2[m2]) - 2.0f * (he0 * c.x + he1 * c.y);
        KNN_UPD(dA, m,  ad0, ad1, ad2, ai0, ai1, ai2);
        KNN_UPD(dB, m2, bd0, bd1, bd2, bi0, bi1, bi2);
    }
    KNN_UPD(bd0, bi0, ad0, ad1, ad2, ai0, ai1, ai2);
    KNN_UPD(bd1, bi1, ad0, ad1, ad2, ai0, ai1, ai2);
    KNN_UPD(bd2, bi2, ad0, ad1, ad2, ai0, ai1, ai2);

    if (half == 1) {
        s_bd[n] = make_float4(ad0, ad1, ad2, 0.0f);
        s_bi[n] = make_int4(ai0, ai1, ai2, 0);
    }
    __syncthreads();
    if (half == 0) {
        float4 pd = s_bd[n]; int4 pi = s_bi[n];
        KNN_UPD(pd.x, pi.x, ad0, ad1, ad2, ai0, ai1, ai2);
        KNN_UPD(pd.y, pi.y, ad0, ad1, ad2, ai0, ai1, ai2);
        KNN_UPD(pd.z, pi.z, ad0, ad1, ad2, ai0, ai1, ai2);
        idx[b * NN + n] = (unsigned)ai0 | ((unsigned)ai1 << 8) | ((unsigned)ai2 << 16);
    }
}

// ---------------------------------------------------------------------------
// Phase 4: decoder MLP, EDGE-parallel (verbatim from round 14).
// ---------------------------------------------------------------------------
__global__ __launch_bounds__(256) void k_mlp_dec_edge(
    const float*  __restrict__ dw1, const float* __restrict__ db1,
    const float*  __restrict__ dw2, const float* __restrict__ db2,
    const float*  __restrict__ dw3, const float* __restrict__ db3,
    const float4* __restrict__ tmp,
    const unsigned int* __restrict__ idx,
    float4*       __restrict__ pd)
{
    const int n = threadIdx.x;
    const int b = blockIdx.x;
    const int k = blockIdx.y;

    float4 t = tmp[b * NN + n];
    float he0 = t.x, he1 = t.y;
    unsigned pi = idx[b * NN + n];
    int j = (pi >> (8 * k)) & 255;
    float4 tj = tmp[b * NN + j];

    f32x16 Ba = ldw16(db1), Bb = ldw16(db1 + 16);
    ROW1(he0, dw1 + 0 * BIG, Ba, Bb);
    ROW1(he1, dw1 + 1 * BIG, Ba, Bb);
    float p20 = tj.x - he0, p21 = tj.y - he1;
    ROW1(p20, dw1 + 2 * BIG, Ba, Bb);
    ROW1(p21, dw1 + 3 * BIG, Ba, Bb);
    Ba = relu16(Ba); Bb = relu16(Bb);

    f32x4v ove2 = ldw4(db3);
    { L2S(dw2, db2, 0,  Ba, Bb, QF0); L3DS(0,  QF0); }
    { L2S(dw2, db2, 16, Ba, Bb, QF1); L3DS(16, QF1); }
    pd[(k * NB + b) * NN + n] = make_float4(ove2[0], ove2[1], ove2[2], ove2[3]);
}

// ---------------------------------------------------------------------------
// Phase 5: combine decoder partials -> final output (verbatim from round 14).
// ---------------------------------------------------------------------------
__global__ __launch_bounds__(256) void k_comb_dec(
    const float4* __restrict__ pd,
    float4*       __restrict__ out)
{
    int g = blockIdx.x * 256 + threadIdx.x;   // [0, NB*NN)
    float4 p0 = pd[0 * NB * NN + g];
    float4 p1 = pd[1 * NB * NN + g];
    float4 p2 = pd[2 * NB * NN + g];
    float4 ov;
    ov.x = ((p0.x + p1.x) + p2.x) / 3.0f;
    ov.y = ((p0.y + p1.y) + p2.y) / 3.0f;
    ov.z = ((p0.z + p1.z) + p2.z) / 3.0f;
    ov.w = ((p0.w + p1.w) + p2.w) / 3.0f;
    out[g] = ov;
}

// ---------------------------------------------------------------------------
extern "C" void kernel_launch(void* const* d_in, const int* in_sizes, int n_in,
                              void* d_out, int out_size, void* d_ws, size_t ws_size,
                              hipStream_t stream) {
    const float* x   = (const float*)d_in[0];
    const float* gmm = (const float*)d_in[1];
    const float* bta = (const float*)d_in[2];
    const float* ew1 = (const float*)d_in[3];
    const float* eb1 = (const float*)d_in[4];
    const float* ew2 = (const float*)d_in[5];
    const float* eb2 = (const float*)d_in[6];
    const float* ew3 = (const float*)d_in[7];
    const float* eb3 = (const float*)d_in[8];
    const float* dw1 = (const float*)d_in[9];
    const float* db1 = (const float*)d_in[10];
    const float* dw2 = (const float*)d_in[11];
    const float* db2 = (const float*)d_in[12];
    const float* dw3 = (const float*)d_in[13];
    const float* db3 = (const float*)d_in[14];

    double*       ws   = (double*)d_ws;
    unsigned int* idxb = (unsigned int*)((char*)d_ws + 64);            // 1 MB
    char*         pbuf = (char*)d_ws + 64 + (size_t)NB * NN * 4;       // 12.6 MB
    float2*       pe   = (float2*)pbuf;
    float4*       pd   = (float4*)pbuf;
    float4*       tmp  = (float4*)d_out;

    hipLaunchKernelGGL(k_zero_ws, dim3(1), dim3(64), 0, stream, ws);
    hipLaunchKernelGGL(k_bn_reduce, dim3(256), dim3(256), 0, stream,
                       (const float4*)x, ws);
    hipLaunchKernelGGL(k_knn_enc, dim3(NB), dim3(512), 0, stream,
                       x, gmm, bta, ws, tmp, idxb);
    hipLaunchKernelGGL(k_mlp_enc_edge, dim3(NB, NK), dim3(256), 0, stream,
                       ew1, eb1, ew2, eb2, ew3, eb3, tmp, idxb, pe);
    hipLaunchKernelGGL(k_knn_dec, dim3(NB), dim3(512), 0, stream,
                       pe, tmp, idxb);
    hipLaunchKernelGGL(k_mlp_dec_edge, dim3(NB, NK), dim3(256), 0, stream,
                       dw1, db1, dw2, db2, dw3, db3, tmp, idxb, pd);
    hipLaunchKernelGGL(k_comb_dec, dim3(NB), dim3(256), 0, stream,
                       pd, tmp);
}